// Round 15
// baseline (918.392 us; speedup 1.0000x reference)
//
#include <hip/hip_runtime.h>
#include <hip/hip_bf16.h>

#define BATCH 32
#define E 256
#define V 32000
#define NSTEP 128
#define M_TOTAL (BATCH * NSTEP)   // 4096
#define BM 128
#define BN2 128
#define NT (V / BN2)              // 250 n-tiles
#define NITEMS (32 * NT)          // 8000 work items
#define NTRB 224                  // transpose/gemm-only blocks
#define NPART (4 * NT)            // 1000 partial stripes
#define L2E 1.4426950408889634f

typedef __attribute__((ext_vector_type(4))) float f32x4;
typedef __attribute__((ext_vector_type(2))) float f32x2;
typedef __attribute__((ext_vector_type(8))) short s16x8;
typedef __attribute__((ext_vector_type(4))) unsigned int u32x4;

static __device__ __forceinline__ short f2bf(float v) {
    __hip_bfloat16 h = __float2bfloat16(v);
    return *reinterpret_cast<short*>(&h);
}

static __device__ __forceinline__ unsigned char f2fp8(float v) {
    int p = __builtin_amdgcn_cvt_pk_fp8_f32(v, v, 0, false);
    return (unsigned char)(p & 0xff);
}
template<bool HI>
static __device__ __forceinline__ f32x2 fp8x2_to_f32(unsigned int x) {
    return __builtin_amdgcn_cvt_pk_f32_fp8((int)x, HI);
}

// frag-major byte position within a 256-B row: element e -> lk*64 + kk*8 + j
static __device__ __forceinline__ int fragpos(int e) {
    return ((e >> 3) & 3) * 64 + (e >> 5) * 8 + (e & 7);
}

static __device__ __forceinline__ long long ll2(unsigned int a, unsigned int b) {
    return (long long)(((unsigned long long)b << 32) | a);
}

static __device__ __forceinline__ void gload_lds16(const void* g, void* l) {
    __builtin_amdgcn_global_load_lds((const __attribute__((address_space(1))) void*)g,
                                     (__attribute__((address_space(3))) void*)l,
                                     16, 0, 0);
}

template<int CTRL>
static __device__ __forceinline__ float dpp_add(float v) {
    int i = __builtin_amdgcn_update_dpp(0, __builtin_bit_cast(int, v), CTRL, 0xF, 0xF, false);
    return v + __builtin_bit_cast(float, i);
}
static __device__ __forceinline__ float row16_sum(float v) {
    v = dpp_add<0x121>(v);
    v = dpp_add<0x122>(v);
    v = dpp_add<0x124>(v);
    v = dpp_add<0x128>(v);
    return v;
}

// ---------------------------------------------------------------------------
// Mega kernel: 256 blocks x 512 threads, 83 KB LDS (forces 1 block/CU so all
// blocks are co-resident; traj blocks are bid 0..31, dispatched first).
//   bid 0..31 : RNN trajectory (producer); zsb8 row = t*32 + b; signals
//               grpdone[t/8] after each 8-step flush (fence + atomicAdd).
//   bid 32..255: vocab_w transpose -> frag-major fp8; signals tdone.
//   then ALL  : gemm workers pulling (bm, nt) items bm-major from an atomic
//               queue; spin on grpdone; double-buffered B + A prefetch;
//               LSE exp-sums stored to unique (nt,wc) partial stripes.
// ---------------------------------------------------------------------------
__global__ __launch_bounds__(512, 2) void mega_kernel(
        const float* __restrict__ latent, const int* __restrict__ zi,
        const float* __restrict__ w, const float* __restrict__ vb,
        unsigned char* __restrict__ zsb8, unsigned char* __restrict__ wt8,
        float* __restrict__ partial, int* __restrict__ ctrs) {
    __shared__ __align__(16) unsigned char smem[84992];   // >80KB -> 1 block/CU
    __shared__ int sk;

    const int tid  = threadIdx.x;
    const int bid  = blockIdx.x;
    const int lane = tid & 63;

    if (bid < BATCH) {
        // ===================== trajectory (producer) =====================
        short (*zsh)[E]  = (short(*)[E])smem;             // [2][256] bf16
        float (*red)[16] = (float(*)[16])(smem + 1024);   // [2][16]

        const int b  = bid;
        const int wv = tid >> 6;
        const int lm = lane & 15;
        const int g  = lane >> 4;
        const float* tr = latent + (size_t)zi[b] * (E * E);

        s16x8 bfrag[2][8];
        #pragma unroll
        for (int nt = 0; nt < 2; ++nt)
            #pragma unroll
            for (int kk = 0; kk < 8; ++kk) {
                s16x8 fr;
                #pragma unroll
                for (int j = 0; j < 8; ++j)
                    fr[j] = f2bf(tr[(size_t)(kk * 32 + g * 8 + j) * E + wv * 32 + nt * 16 + lm]);
                bfrag[nt][kk] = fr;
            }

        if (tid < E) zsh[0][tid] = f2bf(tr[tid]);
        {
            float v = (tid < E) ? tr[tid] : 0.f;
            float a = row16_sum(v), a2 = row16_sum(v * v);
            a  += __shfl_xor(a, 16);  a2 += __shfl_xor(a2, 16);
            a  += __shfl_xor(a, 32);  a2 += __shfl_xor(a2, 32);
            if (lane == 0) { red[1][wv] = a; red[1][8 + wv] = a2; }
        }
        __syncthreads();

        float scale_prev = 1.0f;
        const int p0i = fragpos(wv * 32 + lm);
        const int p1i = fragpos(wv * 32 + 16 + lm);

        for (int tb = 0; tb < NSTEP; tb += 8) {
            unsigned char eb0[8], eb1[8];
            #pragma unroll
            for (int s = 0; s < 8; ++s) {
                const int t = tb + s;
                const short* zrd = zsh[t & 1];
                s16x8 a[8];
                #pragma unroll
                for (int kk = 0; kk < 8; ++kk)
                    a[kk] = *(const s16x8*)((const char*)zrd + kk * 64 + g * 16);

                const float* rd = red[(t + 1) & 1];
                f32x4 q0 = *(const f32x4*)&rd[0], q1 = *(const f32x4*)&rd[4];
                f32x4 v0 = *(const f32x4*)&rd[8], v1 = *(const f32x4*)&rd[12];
                float ts  = (q0[0]+q0[1]+q0[2]+q0[3]) + (q1[0]+q1[1]+q1[2]+q1[3]);
                float ts2 = (v0[0]+v0[1]+v0[2]+v0[3]) + (v1[0]+v1[1]+v1[2]+v1[3]);
                float var = fmaxf((ts2 - ts * ts * (1.0f / 256.0f)) * (1.0f / 255.0f), 0.f);
                const float scale_cur = 0.113f / (1e-5f + scale_prev * sqrtf(var));

                f32x4 a0l = {}, a0h = {}, a1l = {}, a1h = {};
                #pragma unroll
                for (int kk = 0; kk < 4; ++kk) {
                    a0l = __builtin_amdgcn_mfma_f32_16x16x32_bf16(a[kk], bfrag[0][kk], a0l, 0, 0, 0);
                    a1l = __builtin_amdgcn_mfma_f32_16x16x32_bf16(a[kk], bfrag[1][kk], a1l, 0, 0, 0);
                }
                #pragma unroll
                for (int kk = 4; kk < 8; ++kk) {
                    a0h = __builtin_amdgcn_mfma_f32_16x16x32_bf16(a[kk], bfrag[0][kk], a0h, 0, 0, 0);
                    a1h = __builtin_amdgcn_mfma_f32_16x16x32_bf16(a[kk], bfrag[1][kk], a1h, 0, 0, 0);
                }

                const float u0 = scale_prev * (a0l[0] + a0h[0]);
                const float u1 = scale_prev * (a1l[0] + a1h[0]);
                if (g == 0) {
                    zsh[(t + 1) & 1][wv * 32 + lm]      = f2bf(u0);
                    zsh[(t + 1) & 1][wv * 32 + 16 + lm] = f2bf(u1);
                    eb0[s] = f2fp8(scale_cur * u0);
                    eb1[s] = f2fp8(scale_cur * u1);
                }

                float su  = row16_sum(u0 + u1);
                float su2 = row16_sum(u0 * u0 + u1 * u1);
                if (lane == 0) { red[t & 1][wv] = su; red[t & 1][8 + wv] = su2; }
                scale_prev = scale_cur;
                __syncthreads();
            }
            // flush rows (tb+s)*32 + b (stride 32*E bytes)
            if (g == 0) {
                unsigned char* zr = zsb8 + ((size_t)(tb * 32 + b)) * E;
                #pragma unroll
                for (int s = 0; s < 8; ++s) {
                    zr[s * (32 * E) + p0i] = eb0[s];
                    zr[s * (32 * E) + p1i] = eb1[s];
                }
            }
            __syncthreads();   // drain flush stores (compiler waits vmcnt)
            if (tid == 0) { __threadfence(); atomicAdd(&ctrs[2 + (tb >> 3)], 1); }
        }
    } else {
        // ===================== transpose (fp8 frag-major) =====================
        float (*tile)[65] = (float(*)[65])smem;
        for (int it = 0; it < 9; ++it) {
            const int bb = (bid - BATCH) + NTRB * it;
            if (bb < 2000) {
                const int k0 = (bb & 3) * 64;
                const int n0 = (bb >> 2) * 64;
                const int c  = tid & 63;
                const int r8 = tid >> 6;
                __syncthreads();
                #pragma unroll
                for (int r = r8; r < 64; r += 8)
                    tile[r][c] = w[(size_t)(k0 + r) * V + n0 + c];
                __syncthreads();
                const int fp = fragpos(k0 + c);
                #pragma unroll
                for (int r = r8; r < 64; r += 8)
                    wt8[(size_t)(n0 + r) * E + fp] = f2fp8(tile[c][r]);
            }
        }
        __syncthreads();
        if (tid == 0) { __threadfence(); atomicAdd(&ctrs[1], 1); }
    }

    // ===================== wait: transpose complete =====================
    if (tid == 0) {
        while (atomicAdd(&ctrs[1], 0) < NTRB) __builtin_amdgcn_s_sleep(32);
    }
    __syncthreads();
    __threadfence();

    // ===================== gemm worker =====================
    unsigned char* bpan0 = smem;
    unsigned char* bpan1 = smem + 32768;
    const int w8 = tid >> 6;
    const int wr = w8 >> 2, wc = w8 & 3;   // 2 x 4 wave grid, wave tile 64x32
    const int lm = lane & 15, lk = lane >> 4;

    long long aregA[4][8], aregB[4][8];
    f32x4 acc[4][2];
    float bias[2];
    int fencedg = -1;

    auto GRAB = [&]() -> int {
        __syncthreads();
        if (tid == 0) {
            int k = atomicAdd(&ctrs[0], 1);
            if (k < NITEMS) {
                const int gq = (k / NT) >> 1;
                while (atomicAdd(&ctrs[2 + gq], 0) < BATCH) __builtin_amdgcn_s_sleep(16);
            }
            sk = k;
        }
        __syncthreads();
        const int k = sk;
        if (k < NITEMS) {
            const int gq = (k / NT) >> 1;
            if (gq > fencedg) { __threadfence(); fencedg = gq; }
        }
        return k;
    };

    auto STAGEB = [&](int nt, unsigned char* dst) {
        const size_t gbase = (size_t)(nt * BN2) * E;
        #pragma unroll
        for (int j = 0; j < 4; ++j) {
            const int c   = j * 512 + tid;
            const int row = c >> 4;
            const int gsl = ((c & 15) - row) & 15;
            gload_lds16(wt8 + gbase + (size_t)row * E + gsl * 16, dst + c * 16);
        }
    };

    auto LOADA = [&](int bm, long long (&areg)[4][8]) {
        const int mw = bm * BM + wr * 64;
        #pragma unroll
        for (int rt = 0; rt < 4; ++rt)
            #pragma unroll
            for (int kp = 0; kp < 4; ++kp) {
                u32x4 v = *(const u32x4*)(zsb8 + (size_t)(mw + rt * 16 + lm) * E + lk * 64 + kp * 16);
                areg[rt][2 * kp]     = ll2(v[0], v[1]);
                areg[rt][2 * kp + 1] = ll2(v[2], v[3]);
            }
    };

    auto COMPUTE = [&](const unsigned char* bp, const long long (&areg)[4][8], int nt) {
        const int n0 = nt * BN2;
        bias[0] = vb[n0 + wc * 32 + lm] * L2E;
        bias[1] = vb[n0 + wc * 32 + 16 + lm] * L2E;
        #pragma unroll
        for (int rt = 0; rt < 4; ++rt) { acc[rt][0] = (f32x4){}; acc[rt][1] = (f32x4){}; }
        #pragma unroll
        for (int kp = 0; kp < 4; ++kp) {
            long long blo[2], bhi[2];
            #pragma unroll
            for (int nti = 0; nti < 2; ++nti) {
                const int rn   = wc * 32 + nti * 16 + lm;
                const int slot = (lk * 4 + kp + rn) & 15;
                u32x4 bv = *(const u32x4*)(bp + rn * 256 + slot * 16);
                blo[nti] = ll2(bv[0], bv[1]);
                bhi[nti] = ll2(bv[2], bv[3]);
            }
            #pragma unroll
            for (int rt = 0; rt < 4; ++rt) {
                acc[rt][0] = __builtin_amdgcn_mfma_f32_16x16x32_fp8_fp8(areg[rt][2 * kp], blo[0], acc[rt][0], 0, 0, 0);
                acc[rt][1] = __builtin_amdgcn_mfma_f32_16x16x32_fp8_fp8(areg[rt][2 * kp], blo[1], acc[rt][1], 0, 0, 0);
            }
            #pragma unroll
            for (int rt = 0; rt < 4; ++rt) {
                acc[rt][0] = __builtin_amdgcn_mfma_f32_16x16x32_fp8_fp8(areg[rt][2 * kp + 1], bhi[0], acc[rt][0], 0, 0, 0);
                acc[rt][1] = __builtin_amdgcn_mfma_f32_16x16x32_fp8_fp8(areg[rt][2 * kp + 1], bhi[1], acc[rt][1], 0, 0, 0);
            }
        }
    };

    auto EPI = [&](int k) {
        const int nt = k / NT == 0 ? k : k % NT;   // nt = k % NT (avoid double div)
        const int bm = k / NT;
        const int cr = lane >> 4;
        #pragma unroll
        for (int rt = 0; rt < 4; ++rt) {
            f32x4 ex;
            #pragma unroll
            for (int r = 0; r < 4; ++r)
                ex[r] = __builtin_amdgcn_exp2f(acc[rt][0][r] * L2E + bias[0])
                      + __builtin_amdgcn_exp2f(acc[rt][1][r] * L2E + bias[1]);
            #pragma unroll
            for (int r = 0; r < 4; ++r) ex[r] = row16_sum(ex[r]);
            if (lm == 0)
                *(f32x4*)(partial + (size_t)(nt * 4 + wc) * M_TOTAL
                          + bm * BM + wr * 64 + rt * 16 + cr * 4) = ex;
        }
    };

    int kA = GRAB();
    if (kA < NITEMS) {
        STAGEB(kA % NT, bpan0);
        LOADA(kA / NT, aregA);
        __syncthreads();     // B0 + A0 resident
        for (;;) {
            int kB = GRAB();
            if (kB < NITEMS) { STAGEB(kB % NT, bpan1); LOADA(kB / NT, aregB); }
            COMPUTE(bpan0, aregA, kA % NT);
            EPI(kA);
            __syncthreads();
            if (kB >= NITEMS) break;
            kA = kB;
            int kC = GRAB();
            if (kC < NITEMS) { STAGEB(kC % NT, bpan0); LOADA(kC / NT, aregA); }
            COMPUTE(bpan1, aregB, kA % NT);
            EPI(kA);
            __syncthreads();
            if (kC >= NITEMS) break;
            kA = kC;
        }
    }
}

// ---------------------------------------------------------------------------
// Finalize: per zrow (= t*32+b): target logit via fp8 dot + log of the
// 1000-stripe partial sum; out/y indexed [b][t].
// ---------------------------------------------------------------------------
__global__ __launch_bounds__(256) void finalize_kernel(const unsigned char* __restrict__ zsb8,
                                                       const unsigned char* __restrict__ wt8,
                                                       const float* __restrict__ vb,
                                                       const int* __restrict__ y,
                                                       const float* __restrict__ partial,
                                                       float* __restrict__ out) {
    __shared__ float s[16][17];
    __shared__ float lg[16];
    const int tid = threadIdx.x;
    const int jp = tid >> 4, r = tid & 15;
    const int rowbase = blockIdx.x * 16;

    float acc = 0.f;
    for (int j = jp; j < NPART; j += 16)
        acc += partial[(size_t)j * M_TOTAL + rowbase + r];
    s[jp][r] = acc;

    // target logit (frag-major permutation cancels in the dot)
    const int lane = tid & 63;
    const int rw = lane >> 4, kl = lane & 15;
    const int zrow = rowbase + (tid >> 6) * 4 + rw;
    const int oidx = (zrow & 31) * NSTEP + (zrow >> 5);
    const int yrow = y[oidx];

    u32x4 za = *(const u32x4*)(zsb8 + (size_t)zrow * E + kl * 16);
    u32x4 wa = *(const u32x4*)(wt8 + (size_t)yrow * E + kl * 16);
    float d = 0.f;
    #pragma unroll
    for (int q = 0; q < 4; ++q) {
        f32x2 a0 = fp8x2_to_f32<false>(za[q]), b0 = fp8x2_to_f32<false>(wa[q]);
        f32x2 a1 = fp8x2_to_f32<true>(za[q]),  b1 = fp8x2_to_f32<true>(wa[q]);
        d += a0[0] * b0[0] + a0[1] * b0[1] + a1[0] * b1[0] + a1[1] * b1[1];
    }
    const float logit = row16_sum(d) + vb[yrow];
    if (kl == 0) lg[(tid >> 6) * 4 + rw] = logit;
    __syncthreads();

    if (tid < 16) {
        float tot = 0.f;
        #pragma unroll
        for (int k = 0; k < 16; ++k) tot += s[k][tid];
        const int zr2 = rowbase + tid;
        out[(zr2 & 31) * NSTEP + (zr2 >> 5)] = lg[tid] - logf(tot);
    }
}

// ---------------------------------------------------------------------------
extern "C" void kernel_launch(void* const* d_in, const int* in_sizes, int n_in,
                              void* d_out, int out_size, void* d_ws, size_t ws_size,
                              hipStream_t stream) {
    const float* latent  = (const float*)d_in[0];
    const float* vocab_w = (const float*)d_in[1];
    const float* vocab_b = (const float*)d_in[2];
    const int*   zi      = (const int*)d_in[3];
    const int*   y       = (const int*)d_in[4];
    float* out = (float*)d_out;

    char* ws = (char*)d_ws;
    float*         partial = (float*)(ws);                       // 1000*4096*4 = 16,384,000 B
    unsigned char* zsb8    = (unsigned char*)(ws + 16384000);    // 1 MB
    unsigned char* wt8     = (unsigned char*)(ws + 16384000 + 1048576);   // 8 MB
    int*           ctrs    = (int*)(ws + 16384000 + 1048576 + 8192000);   // 128 B

    hipMemsetAsync(ctrs, 0, 128, stream);
    hipLaunchKernelGGL(mega_kernel, dim3(256), dim3(512), 0, stream,
                       latent, zi, vocab_w, vocab_b, zsb8, wt8, partial, ctrs);
    hipLaunchKernelGGL(finalize_kernel, dim3(M_TOTAL / 16), dim3(256), 0, stream,
                       zsb8, wt8, vocab_b, y, partial, out);
}

// Round 16
// 527.185 us; speedup vs baseline: 1.7421x; 1.7421x over previous
//
#include <hip/hip_runtime.h>
#include <hip/hip_bf16.h>

#define BATCH 32
#define E 256
#define V 32000
#define NSTEP 128
#define M_TOTAL (BATCH * NSTEP)   // 4096
#define BM 128
#define BN2 128
#define NT (V / BN2)              // 250 n-tiles
#define NITEMS (32 * NT)          // 8000 work items
#define NTRB 224                  // transpose blocks
#define NPART (4 * NT)            // 1000 partial stripes
#define L2E 1.4426950408889634f
// padded counter slots (32 ints = 128 B apart)
#define C_QUEUE 0
#define C_TDONE 32
#define C_GRP(g) (64 + 32 * (g))

typedef __attribute__((ext_vector_type(4))) float f32x4;
typedef __attribute__((ext_vector_type(2))) float f32x2;
typedef __attribute__((ext_vector_type(8))) short s16x8;
typedef __attribute__((ext_vector_type(4))) unsigned int u32x4;

static __device__ __forceinline__ short f2bf(float v) {
    __hip_bfloat16 h = __float2bfloat16(v);
    return *reinterpret_cast<short*>(&h);
}

static __device__ __forceinline__ unsigned char f2fp8(float v) {
    int p = __builtin_amdgcn_cvt_pk_fp8_f32(v, v, 0, false);
    return (unsigned char)(p & 0xff);
}
template<bool HI>
static __device__ __forceinline__ f32x2 fp8x2_to_f32(unsigned int x) {
    return __builtin_amdgcn_cvt_pk_f32_fp8((int)x, HI);
}

// frag-major byte position within a 256-B row: element e -> lk*64 + kk*8 + j
static __device__ __forceinline__ int fragpos(int e) {
    return ((e >> 3) & 3) * 64 + (e >> 5) * 8 + (e & 7);
}

static __device__ __forceinline__ long long ll2(unsigned int a, unsigned int b) {
    return (long long)(((unsigned long long)b << 32) | a);
}

static __device__ __forceinline__ void gload_lds16(const void* g, void* l) {
    __builtin_amdgcn_global_load_lds((const __attribute__((address_space(1))) void*)g,
                                     (__attribute__((address_space(3))) void*)l,
                                     16, 0, 0);
}

static __device__ __forceinline__ int ctr_load(const int* p) {
    return __hip_atomic_load(p, __ATOMIC_RELAXED, __HIP_MEMORY_SCOPE_AGENT);
}

template<int CTRL>
static __device__ __forceinline__ float dpp_add(float v) {
    int i = __builtin_amdgcn_update_dpp(0, __builtin_bit_cast(int, v), CTRL, 0xF, 0xF, false);
    return v + __builtin_bit_cast(float, i);
}
static __device__ __forceinline__ float row16_sum(float v) {
    v = dpp_add<0x121>(v);
    v = dpp_add<0x122>(v);
    v = dpp_add<0x124>(v);
    v = dpp_add<0x128>(v);
    return v;
}

// ---------------------------------------------------------------------------
// Mega kernel: 256 blocks x 512 threads, 83 KB LDS (1 block/CU, co-resident).
//   bid 0..31 : RNN trajectory (producer); zsb8 row = t*32 + b; signals
//               C_GRP(t/8) after each 8-step flush (fence + padded atomic).
//   bid 32..255: vocab_w transpose -> frag-major fp8; signals C_TDONE.
//   then ALL  : gemm workers; chunked (4) atomic queue claims; readiness
//               polled with plain agent-scope loads + s_sleep (NO RMW spin).
// ---------------------------------------------------------------------------
__global__ __launch_bounds__(512, 2) void mega_kernel(
        const float* __restrict__ latent, const int* __restrict__ zi,
        const float* __restrict__ w, const float* __restrict__ vb,
        unsigned char* __restrict__ zsb8, unsigned char* __restrict__ wt8,
        float* __restrict__ partial, int* __restrict__ ctrs) {
    __shared__ __align__(16) unsigned char smem[84992];   // >80KB -> 1 block/CU
    __shared__ int sk;

    const int tid  = threadIdx.x;
    const int bid  = blockIdx.x;
    const int lane = tid & 63;

    if (bid < BATCH) {
        // ===================== trajectory (producer) =====================
        short (*zsh)[E]  = (short(*)[E])smem;             // [2][256] bf16
        float (*red)[16] = (float(*)[16])(smem + 1024);   // [2][16]

        const int b  = bid;
        const int wv = tid >> 6;
        const int lm = lane & 15;
        const int g  = lane >> 4;
        const float* tr = latent + (size_t)zi[b] * (E * E);

        s16x8 bfrag[2][8];
        #pragma unroll
        for (int nt = 0; nt < 2; ++nt)
            #pragma unroll
            for (int kk = 0; kk < 8; ++kk) {
                s16x8 fr;
                #pragma unroll
                for (int j = 0; j < 8; ++j)
                    fr[j] = f2bf(tr[(size_t)(kk * 32 + g * 8 + j) * E + wv * 32 + nt * 16 + lm]);
                bfrag[nt][kk] = fr;
            }

        if (tid < E) zsh[0][tid] = f2bf(tr[tid]);
        {
            float v = (tid < E) ? tr[tid] : 0.f;
            float a = row16_sum(v), a2 = row16_sum(v * v);
            a  += __shfl_xor(a, 16);  a2 += __shfl_xor(a2, 16);
            a  += __shfl_xor(a, 32);  a2 += __shfl_xor(a2, 32);
            if (lane == 0) { red[1][wv] = a; red[1][8 + wv] = a2; }
        }
        __syncthreads();

        float scale_prev = 1.0f;
        const int p0i = fragpos(wv * 32 + lm);
        const int p1i = fragpos(wv * 32 + 16 + lm);

        for (int tb = 0; tb < NSTEP; tb += 8) {
            unsigned char eb0[8], eb1[8];
            #pragma unroll
            for (int s = 0; s < 8; ++s) {
                const int t = tb + s;
                const short* zrd = zsh[t & 1];
                s16x8 a[8];
                #pragma unroll
                for (int kk = 0; kk < 8; ++kk)
                    a[kk] = *(const s16x8*)((const char*)zrd + kk * 64 + g * 16);

                const float* rd = red[(t + 1) & 1];
                f32x4 q0 = *(const f32x4*)&rd[0], q1 = *(const f32x4*)&rd[4];
                f32x4 v0 = *(const f32x4*)&rd[8], v1 = *(const f32x4*)&rd[12];
                float ts  = (q0[0]+q0[1]+q0[2]+q0[3]) + (q1[0]+q1[1]+q1[2]+q1[3]);
                float ts2 = (v0[0]+v0[1]+v0[2]+v0[3]) + (v1[0]+v1[1]+v1[2]+v1[3]);
                float var = fmaxf((ts2 - ts * ts * (1.0f / 256.0f)) * (1.0f / 255.0f), 0.f);
                const float scale_cur = 0.113f / (1e-5f + scale_prev * sqrtf(var));

                f32x4 a0l = {}, a0h = {}, a1l = {}, a1h = {};
                #pragma unroll
                for (int kk = 0; kk < 4; ++kk) {
                    a0l = __builtin_amdgcn_mfma_f32_16x16x32_bf16(a[kk], bfrag[0][kk], a0l, 0, 0, 0);
                    a1l = __builtin_amdgcn_mfma_f32_16x16x32_bf16(a[kk], bfrag[1][kk], a1l, 0, 0, 0);
                }
                #pragma unroll
                for (int kk = 4; kk < 8; ++kk) {
                    a0h = __builtin_amdgcn_mfma_f32_16x16x32_bf16(a[kk], bfrag[0][kk], a0h, 0, 0, 0);
                    a1h = __builtin_amdgcn_mfma_f32_16x16x32_bf16(a[kk], bfrag[1][kk], a1h, 0, 0, 0);
                }

                const float u0 = scale_prev * (a0l[0] + a0h[0]);
                const float u1 = scale_prev * (a1l[0] + a1h[0]);
                if (g == 0) {
                    zsh[(t + 1) & 1][wv * 32 + lm]      = f2bf(u0);
                    zsh[(t + 1) & 1][wv * 32 + 16 + lm] = f2bf(u1);
                    eb0[s] = f2fp8(scale_cur * u0);
                    eb1[s] = f2fp8(scale_cur * u1);
                }

                float su  = row16_sum(u0 + u1);
                float su2 = row16_sum(u0 * u0 + u1 * u1);
                if (lane == 0) { red[t & 1][wv] = su; red[t & 1][8 + wv] = su2; }
                scale_prev = scale_cur;
                __syncthreads();
            }
            if (g == 0) {
                unsigned char* zr = zsb8 + ((size_t)(tb * 32 + b)) * E;
                #pragma unroll
                for (int s = 0; s < 8; ++s) {
                    zr[s * (32 * E) + p0i] = eb0[s];
                    zr[s * (32 * E) + p1i] = eb1[s];
                }
            }
            __syncthreads();   // drains flush stores
            if (tid == 0) { __threadfence(); atomicAdd(&ctrs[C_GRP(tb >> 3)], 1); }
        }
    } else {
        // ===================== transpose (fp8 frag-major) =====================
        float (*tile)[65] = (float(*)[65])smem;
        for (int it = 0; it < 9; ++it) {
            const int bb = (bid - BATCH) + NTRB * it;
            if (bb < 2000) {
                const int k0 = (bb & 3) * 64;
                const int n0 = (bb >> 2) * 64;
                const int c  = tid & 63;
                const int r8 = tid >> 6;
                __syncthreads();
                #pragma unroll
                for (int r = r8; r < 64; r += 8)
                    tile[r][c] = w[(size_t)(k0 + r) * V + n0 + c];
                __syncthreads();
                const int fp = fragpos(k0 + c);
                #pragma unroll
                for (int r = r8; r < 64; r += 8)
                    wt8[(size_t)(n0 + r) * E + fp] = f2fp8(tile[c][r]);
            }
        }
        __syncthreads();
        if (tid == 0) { __threadfence(); atomicAdd(&ctrs[C_TDONE], 1); }
    }

    // ===================== wait: transpose complete (load-spin) =====================
    if (tid == 0) {
        while (ctr_load(&ctrs[C_TDONE]) < NTRB) __builtin_amdgcn_s_sleep(64);
    }
    __syncthreads();
    __threadfence();

    // ===================== gemm worker =====================
    unsigned char* bpan0 = smem;
    unsigned char* bpan1 = smem + 32768;
    const int w8 = tid >> 6;
    const int wr = w8 >> 2, wc = w8 & 3;   // 2 x 4 wave grid, wave tile 64x32
    const int lm = lane & 15, lk = lane >> 4;

    long long aregA[4][8], aregB[4][8];
    f32x4 acc[4][2];
    float bias[2];
    int fencedg = -1;
    int qbase = 0, qcnt = 0;   // tid==0 only: chunked claim FIFO

    auto GRAB = [&]() -> int {
        __syncthreads();
        if (tid == 0) {
            if (qcnt == 0) { qbase = atomicAdd(&ctrs[C_QUEUE], 4); qcnt = 4; }
            const int k = qbase; ++qbase; --qcnt;
            if (k < NITEMS) {
                const int gq = (k / NT) >> 1;
                while (ctr_load(&ctrs[C_GRP(gq)]) < BATCH) __builtin_amdgcn_s_sleep(64);
            }
            sk = k;
        }
        __syncthreads();
        const int k = sk;
        if (k < NITEMS) {
            const int gq = (k / NT) >> 1;
            if (gq > fencedg) { __threadfence(); fencedg = gq; }
        }
        return k;
    };

    auto STAGEB = [&](int nt, unsigned char* dst) {
        const size_t gbase = (size_t)(nt * BN2) * E;
        #pragma unroll
        for (int j = 0; j < 4; ++j) {
            const int c   = j * 512 + tid;
            const int row = c >> 4;
            const int gsl = ((c & 15) - row) & 15;
            gload_lds16(wt8 + gbase + (size_t)row * E + gsl * 16, dst + c * 16);
        }
    };

    auto LOADA = [&](int bm, long long (&areg)[4][8]) {
        const int mw = bm * BM + wr * 64;
        #pragma unroll
        for (int rt = 0; rt < 4; ++rt)
            #pragma unroll
            for (int kp = 0; kp < 4; ++kp) {
                u32x4 v = *(const u32x4*)(zsb8 + (size_t)(mw + rt * 16 + lm) * E + lk * 64 + kp * 16);
                areg[rt][2 * kp]     = ll2(v[0], v[1]);
                areg[rt][2 * kp + 1] = ll2(v[2], v[3]);
            }
    };

    auto COMPUTE = [&](const unsigned char* bp, const long long (&areg)[4][8], int nt) {
        const int n0 = nt * BN2;
        bias[0] = vb[n0 + wc * 32 + lm] * L2E;
        bias[1] = vb[n0 + wc * 32 + 16 + lm] * L2E;
        #pragma unroll
        for (int rt = 0; rt < 4; ++rt) { acc[rt][0] = (f32x4){}; acc[rt][1] = (f32x4){}; }
        #pragma unroll
        for (int kp = 0; kp < 4; ++kp) {
            long long blo[2], bhi[2];
            #pragma unroll
            for (int nti = 0; nti < 2; ++nti) {
                const int rn   = wc * 32 + nti * 16 + lm;
                const int slot = (lk * 4 + kp + rn) & 15;
                u32x4 bv = *(const u32x4*)(bp + rn * 256 + slot * 16);
                blo[nti] = ll2(bv[0], bv[1]);
                bhi[nti] = ll2(bv[2], bv[3]);
            }
            #pragma unroll
            for (int rt = 0; rt < 4; ++rt) {
                acc[rt][0] = __builtin_amdgcn_mfma_f32_16x16x32_fp8_fp8(areg[rt][2 * kp], blo[0], acc[rt][0], 0, 0, 0);
                acc[rt][1] = __builtin_amdgcn_mfma_f32_16x16x32_fp8_fp8(areg[rt][2 * kp], blo[1], acc[rt][1], 0, 0, 0);
            }
            #pragma unroll
            for (int rt = 0; rt < 4; ++rt) {
                acc[rt][0] = __builtin_amdgcn_mfma_f32_16x16x32_fp8_fp8(areg[rt][2 * kp + 1], bhi[0], acc[rt][0], 0, 0, 0);
                acc[rt][1] = __builtin_amdgcn_mfma_f32_16x16x32_fp8_fp8(areg[rt][2 * kp + 1], bhi[1], acc[rt][1], 0, 0, 0);
            }
        }
    };

    auto EPI = [&](int k) {
        const int nt = k % NT;
        const int bm = k / NT;
        const int cr = lane >> 4;
        #pragma unroll
        for (int rt = 0; rt < 4; ++rt) {
            f32x4 ex;
            #pragma unroll
            for (int r = 0; r < 4; ++r)
                ex[r] = __builtin_amdgcn_exp2f(acc[rt][0][r] * L2E + bias[0])
                      + __builtin_amdgcn_exp2f(acc[rt][1][r] * L2E + bias[1]);
            #pragma unroll
            for (int r = 0; r < 4; ++r) ex[r] = row16_sum(ex[r]);
            if (lm == 0)
                *(f32x4*)(partial + (size_t)(nt * 4 + wc) * M_TOTAL
                          + bm * BM + wr * 64 + rt * 16 + cr * 4) = ex;
        }
    };

    int kA = GRAB();
    if (kA < NITEMS) {
        STAGEB(kA % NT, bpan0);
        LOADA(kA / NT, aregA);
        __syncthreads();     // B0 + A0 resident
        for (;;) {
            int kB = GRAB();
            if (kB < NITEMS) { STAGEB(kB % NT, bpan1); LOADA(kB / NT, aregB); }
            COMPUTE(bpan0, aregA, kA % NT);
            EPI(kA);
            __syncthreads();
            if (kB >= NITEMS) break;
            kA = kB;
            int kC = GRAB();
            if (kC < NITEMS) { STAGEB(kC % NT, bpan0); LOADA(kC / NT, aregA); }
            COMPUTE(bpan1, aregB, kA % NT);
            EPI(kA);
            __syncthreads();
            if (kC >= NITEMS) break;
            kA = kC;
        }
    }
}

// ---------------------------------------------------------------------------
// Finalize: per zrow (= t*32+b): target logit via fp8 dot + log of the
// 1000-stripe partial sum; out/y indexed [b][t].
// ---------------------------------------------------------------------------
__global__ __launch_bounds__(256) void finalize_kernel(const unsigned char* __restrict__ zsb8,
                                                       const unsigned char* __restrict__ wt8,
                                                       const float* __restrict__ vb,
                                                       const int* __restrict__ y,
                                                       const float* __restrict__ partial,
                                                       float* __restrict__ out) {
    __shared__ float s[16][17];
    __shared__ float lg[16];
    const int tid = threadIdx.x;
    const int jp = tid >> 4, r = tid & 15;
    const int rowbase = blockIdx.x * 16;

    float acc = 0.f;
    for (int j = jp; j < NPART; j += 16)
        acc += partial[(size_t)j * M_TOTAL + rowbase + r];
    s[jp][r] = acc;

    const int lane = tid & 63;
    const int rw = lane >> 4, kl = lane & 15;
    const int zrow = rowbase + (tid >> 6) * 4 + rw;
    const int oidx = (zrow & 31) * NSTEP + (zrow >> 5);
    const int yrow = y[oidx];

    u32x4 za = *(const u32x4*)(zsb8 + (size_t)zrow * E + kl * 16);
    u32x4 wa = *(const u32x4*)(wt8 + (size_t)yrow * E + kl * 16);
    float d = 0.f;
    #pragma unroll
    for (int q = 0; q < 4; ++q) {
        f32x2 a0 = fp8x2_to_f32<false>(za[q]), b0 = fp8x2_to_f32<false>(wa[q]);
        f32x2 a1 = fp8x2_to_f32<true>(za[q]),  b1 = fp8x2_to_f32<true>(wa[q]);
        d += a0[0] * b0[0] + a0[1] * b0[1] + a1[0] * b1[0] + a1[1] * b1[1];
    }
    const float logit = row16_sum(d) + vb[yrow];
    if (kl == 0) lg[(tid >> 6) * 4 + rw] = logit;
    __syncthreads();

    if (tid < 16) {
        float tot = 0.f;
        #pragma unroll
        for (int k = 0; k < 16; ++k) tot += s[k][tid];
        const int zr2 = rowbase + tid;
        out[(zr2 & 31) * NSTEP + (zr2 >> 5)] = lg[tid] - logf(tot);
    }
}

// ---------------------------------------------------------------------------
extern "C" void kernel_launch(void* const* d_in, const int* in_sizes, int n_in,
                              void* d_out, int out_size, void* d_ws, size_t ws_size,
                              hipStream_t stream) {
    const float* latent  = (const float*)d_in[0];
    const float* vocab_w = (const float*)d_in[1];
    const float* vocab_b = (const float*)d_in[2];
    const int*   zi      = (const int*)d_in[3];
    const int*   y       = (const int*)d_in[4];
    float* out = (float*)d_out;

    char* ws = (char*)d_ws;
    float*         partial = (float*)(ws);                       // 16,384,000 B
    unsigned char* zsb8    = (unsigned char*)(ws + 16384000);    // 1 MB
    unsigned char* wt8     = (unsigned char*)(ws + 16384000 + 1048576);   // 8 MB
    int*           ctrs    = (int*)(ws + 16384000 + 1048576 + 8192000);   // 4 KB padded

    hipMemsetAsync(ctrs, 0, 4096, stream);
    hipLaunchKernelGGL(mega_kernel, dim3(256), dim3(512), 0, stream,
                       latent, zi, vocab_w, vocab_b, zsb8, wt8, partial, ctrs);
    hipLaunchKernelGGL(finalize_kernel, dim3(M_TOTAL / 16), dim3(256), 0, stream,
                       zsb8, wt8, vocab_b, y, partial, out);
}

// Round 17
// 250.387 us; speedup vs baseline: 3.6679x; 2.1055x over previous
//
#include <hip/hip_runtime.h>
#include <hip/hip_bf16.h>

#define BATCH 32
#define E 256
#define V 32000
#define NSTEP 128
#define M_TOTAL (BATCH * NSTEP)   // 4096
#define BM 128
#define BN2 128
#define NBT (V / BN2)             // 250 b-tiles
#define NGRP 8                    // bn groups (== XCDs)
#define L2E 1.4426950408889634f

typedef __attribute__((ext_vector_type(4))) float f32x4;
typedef __attribute__((ext_vector_type(2))) float f32x2;
typedef __attribute__((ext_vector_type(8))) short s16x8;
typedef __attribute__((ext_vector_type(4))) unsigned int u32x4;

static __device__ __forceinline__ short f2bf(float v) {
    __hip_bfloat16 h = __float2bfloat16(v);
    return *reinterpret_cast<short*>(&h);
}

static __device__ __forceinline__ unsigned char f2fp8(float v) {
    int p = __builtin_amdgcn_cvt_pk_fp8_f32(v, v, 0, false);
    return (unsigned char)(p & 0xff);
}
template<bool HI>
static __device__ __forceinline__ f32x2 fp8x2_to_f32(unsigned int x) {
    return __builtin_amdgcn_cvt_pk_f32_fp8((int)x, HI);
}

// frag-major byte position within a 256-B row: element e -> lk*64 + kk*8 + j
static __device__ __forceinline__ int fragpos(int e) {
    return ((e >> 3) & 3) * 64 + (e >> 5) * 8 + (e & 7);
}

static __device__ __forceinline__ long long ll2(unsigned int a, unsigned int b) {
    return (long long)(((unsigned long long)b << 32) | a);
}

static __device__ __forceinline__ void gload_lds16(const void* g, void* l) {
    __builtin_amdgcn_global_load_lds((const __attribute__((address_space(1))) void*)g,
                                     (__attribute__((address_space(3))) void*)l,
                                     16, 0, 0);
}

template<int CTRL>
static __device__ __forceinline__ float dpp_add(float v) {
    int i = __builtin_amdgcn_update_dpp(0, __builtin_bit_cast(int, v), CTRL, 0xF, 0xF, false);
    return v + __builtin_bit_cast(float, i);
}
static __device__ __forceinline__ float row16_sum(float v) {
    v = dpp_add<0x121>(v);
    v = dpp_add<0x122>(v);
    v = dpp_add<0x124>(v);
    v = dpp_add<0x128>(v);
    return v;
}

// ---------------------------------------------------------------------------
// Kernel 1 (merged): blocks 0..31 = RNN trajectory with step-doubling via W²;
// blocks 32.. = vocab_w transpose -> frag-major fp8.
// Trajectory: prologue builds W² = W·W in bf16 B-fragments (MFMA + per-wave
// LDS panel transpose), then 64 rounds each advancing TWO steps (even/odd
// chains, 4 independent MFMA chains, one barrier per round). Even chain
// carries exact scale; odd chain lags one round with alpha tracked exactly.
// Emits fp8, register-buffered, flushed every 4 rounds.
// ---------------------------------------------------------------------------
__global__ __launch_bounds__(512, 2) void traj_transpose_kernel(
        const float* __restrict__ latent, const int* __restrict__ zi,
        const float* __restrict__ w,
        unsigned char* __restrict__ zsb8, unsigned char* __restrict__ wt8) {
    __shared__ __align__(16) unsigned char smem[67840];
    // traj layout: panel [8 waves][256][16] bf16 = 64KB at 0;
    //              uE [2][256] bf16 at 65536; uO [2][256] at 66560;
    //              red [2][32] f32 at 67584.
    const int tid = threadIdx.x;

    if (blockIdx.x >= BATCH) {
        // ---- transpose + convert: vocab_w (E x V f32) -> wt8 frag-major ----
        float (*tile)[65] = (float(*)[65])smem;
        const int bb = blockIdx.x - BATCH;   // 0..1999
        const int k0 = (bb & 3) * 64;
        const int n0 = (bb >> 2) * 64;
        const int c  = tid & 63;
        const int r8 = tid >> 6;
        #pragma unroll
        for (int r = r8; r < 64; r += 8)
            tile[r][c] = w[(size_t)(k0 + r) * V + n0 + c];
        __syncthreads();
        const int fp = fragpos(k0 + c);
        #pragma unroll
        for (int r = r8; r < 64; r += 8)
            wt8[(size_t)(n0 + r) * E + fp] = f2fp8(tile[c][r]);
        return;
    }

    // ---- trajectory: one batch per block, 8 waves ----
    short* panel = (short*)smem;                     // per-wave [256][16]
    short* uE    = (short*)(smem + 65536);           // [2][256]
    short* uO    = (short*)(smem + 66560);           // [2][256]
    float* red   = (float*)(smem + 67584);           // [2][32]

    const int b    = blockIdx.x;
    const int lane = tid & 63;
    const int wv   = tid >> 6;       // 0..7, owns cols [32wv, 32wv+32)
    const int lm   = lane & 15;
    const int g    = lane >> 4;
    const float* tr = latent + (size_t)zi[b] * (E * E);

    // B-frags of W: B[n][k] = W[k][n]
    s16x8 bfragW[2][8];
    #pragma unroll
    for (int nt = 0; nt < 2; ++nt)
        #pragma unroll
        for (int kk = 0; kk < 8; ++kk) {
            s16x8 fr;
            #pragma unroll
            for (int j = 0; j < 8; ++j)
                fr[j] = f2bf(tr[(size_t)(kk * 32 + g * 8 + j) * E + wv * 32 + nt * 16 + lm]);
            bfragW[nt][kk] = fr;
        }

    // u_0 = z_0; sigma_0 partials -> red[1][0..15]
    if (tid < E) uE[tid] = f2bf(tr[tid]);
    {
        float v = (tid < E) ? tr[tid] : 0.f;
        float a = row16_sum(v), a2 = row16_sum(v * v);
        a  += __shfl_xor(a, 16);  a2 += __shfl_xor(a2, 16);
        a  += __shfl_xor(a, 32);  a2 += __shfl_xor(a2, 32);
        if (lane == 0) { red[32 + wv] = a; red[32 + 8 + wv] = a2; }
    }
    __syncthreads();

    auto rsum8 = [](const float* p) -> float {
        f32x4 x0 = *(const f32x4*)p, x1 = *(const f32x4*)(p + 4);
        return (x0[0]+x0[1]+x0[2]+x0[3]) + (x1[0]+x1[1]+x1[2]+x1[3]);
    };
    auto stdev = [](float ts, float ts2) -> float {
        return sqrtf(fmaxf((ts2 - ts * ts * (1.0f / 256.0f)) * (1.0f / 255.0f), 0.f));
    };

    float c_e;   // c_{2r}
    {
        float s0 = stdev(rsum8(&red[32]), rsum8(&red[32 + 8]));
        c_e = 0.113f / (1e-5f + s0);   // c_0
    }

    const int p0i = fragpos(wv * 32 + lm);
    const int p1i = fragpos(wv * 32 + 16 + lm);

    // ---- prologue step: u_1 = c_0 * W^T u_0  (= z_1 exactly) ----
    {
        s16x8 a[8];
        #pragma unroll
        for (int kk = 0; kk < 8; ++kk)
            a[kk] = *(const s16x8*)((const char*)uE + kk * 64 + g * 16);
        f32x4 m0 = {}, m1 = {};
        #pragma unroll
        for (int kk = 0; kk < 8; ++kk) {
            m0 = __builtin_amdgcn_mfma_f32_16x16x32_bf16(a[kk], bfragW[0][kk], m0, 0, 0, 0);
            m1 = __builtin_amdgcn_mfma_f32_16x16x32_bf16(a[kk], bfragW[1][kk], m1, 0, 0, 0);
        }
        const float u1a = c_e * m0[0], u1b = c_e * m1[0];
        if (g == 0) {
            uO[wv * 32 + lm]      = f2bf(u1a);
            uO[wv * 32 + 16 + lm] = f2bf(u1b);
            unsigned char* zr = zsb8 + (size_t)b * NSTEP * E;   // row 0 = z_1
            zr[p0i] = f2fp8(u1a);
            zr[p1i] = f2fp8(u1b);
        }
        float su  = row16_sum(u1a + u1b);
        float su2 = row16_sum(u1a * u1a + u1b * u1b);
        if (lane == 0) { red[32 + 16 + wv] = su; red[32 + 24 + wv] = su2; }
    }
    __syncthreads();

    float c_o, a_o = 1.0f;   // c_{2r+1}, alpha_{2r+1}
    {
        float s1 = stdev(rsum8(&red[32 + 16]), rsum8(&red[32 + 24]));
        c_o = 0.113f / (1e-5f + s1);   // c_1 (alpha_1 = 1)
    }

    // ---- build W^2 B-frags: D = W*W; B2[n][k] = D[k][n] ----
    // (wave-local: MFMA with A = rows of W, B = bfragW; transpose via panel)
    s16x8 bfrag2[2][8];
    short* pan = panel + wv * 4096;   // this wave's [256][16]
    #pragma unroll
    for (int jt = 0; jt < 2; ++jt) {
        for (int it = 0; it < 16; ++it) {
            f32x4 acc4 = {};
            #pragma unroll
            for (int kk = 0; kk < 8; ++kk) {
                const float* ap = tr + (size_t)(16 * it + lm) * E + kk * 32 + g * 8;
                f32x4 w0 = *(const f32x4*)ap, w1 = *(const f32x4*)(ap + 4);
                s16x8 af;
                af[0] = f2bf(w0[0]); af[1] = f2bf(w0[1]); af[2] = f2bf(w0[2]); af[3] = f2bf(w0[3]);
                af[4] = f2bf(w1[0]); af[5] = f2bf(w1[1]); af[6] = f2bf(w1[2]); af[7] = f2bf(w1[3]);
                acc4 = __builtin_amdgcn_mfma_f32_16x16x32_bf16(af, bfragW[jt][kk], acc4, 0, 0, 0);
            }
            short* pw = pan + (16 * it + g * 4) * 16;
            pw[0 * 16 + lm] = f2bf(acc4[0]);
            pw[1 * 16 + lm] = f2bf(acc4[1]);
            pw[2 * 16 + lm] = f2bf(acc4[2]);
            pw[3 * 16 + lm] = f2bf(acc4[3]);
        }
        #pragma unroll
        for (int kk = 0; kk < 8; ++kk) {
            s16x8 fr;
            #pragma unroll
            for (int j = 0; j < 8; ++j)
                fr[j] = pan[(32 * kk + 8 * g + j) * 16 + lm];
            bfrag2[jt][kk] = fr;
        }
    }

    // ---- main loop: 64 rounds, 2 steps each ----
    for (int q = 0; q < 16; ++q) {
        unsigned char eb0[8], eb1[8];   // static-indexed -> registers
        #pragma unroll
        for (int rr = 0; rr < 4; ++rr) {
            const int p = rr & 1;
            const short* pe = uE + p * 256;
            const short* po = uO + p * 256;
            s16x8 ae[8], ao[8];
            #pragma unroll
            for (int kk = 0; kk < 8; ++kk) {
                ae[kk] = *(const s16x8*)((const char*)pe + kk * 64 + g * 16);
                ao[kk] = *(const s16x8*)((const char*)po + kk * 64 + g * 16);
            }

            f32x4 e0 = {}, e1 = {}, o0 = {}, o1 = {};
            #pragma unroll
            for (int kk = 0; kk < 8; ++kk) {
                e0 = __builtin_amdgcn_mfma_f32_16x16x32_bf16(ae[kk], bfrag2[0][kk], e0, 0, 0, 0);
                e1 = __builtin_amdgcn_mfma_f32_16x16x32_bf16(ae[kk], bfrag2[1][kk], e1, 0, 0, 0);
                o0 = __builtin_amdgcn_mfma_f32_16x16x32_bf16(ao[kk], bfrag2[0][kk], o0, 0, 0, 0);
                o1 = __builtin_amdgcn_mfma_f32_16x16x32_bf16(ao[kk], bfrag2[1][kk], o1, 0, 0, 0);
            }

            // u_{2r+2} = c_{2r+1} c_{2r} (W^2)^T u_{2r}   (exact: alpha = 1)
            // u_{2r+3} = c_{2r+1} c_{2r} a_{2r+1} (W^2)^T u_{2r+1} (lagged)
            const float fac_e = c_o * c_e;
            const float fac_o = fac_e * a_o;
            const float ue_a = fac_e * e0[0], ue_b = fac_e * e1[0];
            const float uo_a = fac_o * o0[0], uo_b = fac_o * o1[0];

            if (g == 0) {
                short* we = uE + ((p ^ 1) * 256) + wv * 32;
                short* wo = uO + ((p ^ 1) * 256) + wv * 32;
                we[lm] = f2bf(ue_a);  we[16 + lm] = f2bf(ue_b);
                wo[lm] = f2bf(uo_a);  wo[16 + lm] = f2bf(uo_b);
            }
            float se  = row16_sum(ue_a + ue_b);
            float se2 = row16_sum(ue_a * ue_a + ue_b * ue_b);
            float so  = row16_sum(uo_a + uo_b);
            float so2 = row16_sum(uo_a * uo_a + uo_b * uo_b);
            if (lane == 0) {
                float* rp = red + p * 32;
                rp[wv] = se; rp[8 + wv] = se2; rp[16 + wv] = so; rp[24 + wv] = so2;
            }
            __syncthreads();

            const float* rp = red + p * 32;
            const float sig_e = stdev(rsum8(&rp[0]),  rsum8(&rp[8]));
            const float sig_o = stdev(rsum8(&rp[16]), rsum8(&rp[24]));
            const float c_e_new = 0.113f / (1e-5f + sig_e);          // c_{2r+2}
            const float a_o_new = c_e_new / c_e;                     // alpha_{2r+3}
            const float c_o_new = 0.113f / (1e-5f + a_o_new * sig_o); // c_{2r+3}

            eb0[rr * 2]     = f2fp8(ue_a);
            eb1[rr * 2]     = f2fp8(ue_b);
            eb0[rr * 2 + 1] = f2fp8(a_o_new * uo_a);
            eb1[rr * 2 + 1] = f2fp8(a_o_new * uo_b);

            c_e = c_e_new; c_o = c_o_new; a_o = a_o_new;
        }
        // flush: rows 8q+1 .. 8q+8 hold z_{8q+2} .. z_{8q+9}
        if (g == 0) {
            unsigned char* zr = zsb8 + ((size_t)b * NSTEP + 8 * q + 1) * E;
            #pragma unroll
            for (int s = 0; s < 8; ++s)
                if (8 * q + 1 + s < NSTEP) {
                    zr[s * E + p0i] = eb0[s];
                    zr[s * E + p1i] = eb1[s];
                }
        }
    }
}

// ---------------------------------------------------------------------------
// Kernel 2: persistent fp8 GEMM, 2-deep acc pipeline (R14, unchanged).
// ---------------------------------------------------------------------------
__global__ __launch_bounds__(512, 2) void gemm_lse_kernel(const unsigned char* __restrict__ zsb8,
                                                          const unsigned char* __restrict__ wt8,
                                                          const float* __restrict__ vb,
                                                          float* __restrict__ partial) {
    __shared__ unsigned char bpan0[BN2 * E];    // 32 KB
    __shared__ unsigned char bpan1[BN2 * E];    // 32 KB

    const int tid  = threadIdx.x;
    const int lane = tid & 63;
    const int w    = tid >> 6;         // 0..7
    const int grp  = blockIdx.x & 7;
    const int bm   = blockIdx.x >> 3;  // 0..31
    const int m0   = bm * BM;
    const int t0   = (NBT * grp) >> 3;
    const int t1   = (NBT * (grp + 1)) >> 3;

    const int wr = w >> 2, wc = w & 3;
    const int lm = lane & 15, lk = lane >> 4;
    const int mw = m0 + wr * 64;

    long long areg[4][8];
    #pragma unroll
    for (int rt = 0; rt < 4; ++rt)
        #pragma unroll
        for (int kp = 0; kp < 4; ++kp) {
            u32x4 v = *(const u32x4*)(zsb8 + (size_t)(mw + rt * 16 + lm) * E + lk * 64 + kp * 16);
            areg[rt][2 * kp]     = ll2(v[0], v[1]);
            areg[rt][2 * kp + 1] = ll2(v[2], v[3]);
        }

    float rs[4][4] = {};

    auto STAGE = [&](int tile, unsigned char* dst) {
        const size_t gbase = (size_t)(tile * BN2) * E;
        #pragma unroll
        for (int j = 0; j < 4; ++j) {
            const int c   = j * 512 + tid;
            const int row = c >> 4;
            const int gsl = ((c & 15) - row) & 15;
            gload_lds16(wt8 + gbase + (size_t)row * E + gsl * 16, dst + c * 16);
        }
    };

    auto COMPUTE = [&](const unsigned char* bp, f32x4 (&acc)[4][2], float (&bias)[2], int tile) {
        const int n0 = tile * BN2;
        bias[0] = vb[n0 + wc * 32 + lm] * L2E;
        bias[1] = vb[n0 + wc * 32 + 16 + lm] * L2E;
        #pragma unroll
        for (int rt = 0; rt < 4; ++rt) { acc[rt][0] = (f32x4){}; acc[rt][1] = (f32x4){}; }
        #pragma unroll
        for (int kp = 0; kp < 4; ++kp) {
            long long blo[2], bhi[2];
            #pragma unroll
            for (int nt = 0; nt < 2; ++nt) {
                const int rn   = wc * 32 + nt * 16 + lm;
                const int slot = (lk * 4 + kp + rn) & 15;
                u32x4 bv = *(const u32x4*)(bp + rn * 256 + slot * 16);
                blo[nt] = ll2(bv[0], bv[1]);
                bhi[nt] = ll2(bv[2], bv[3]);
            }
            #pragma unroll
            for (int rt = 0; rt < 4; ++rt) {
                acc[rt][0] = __builtin_amdgcn_mfma_f32_16x16x32_fp8_fp8(areg[rt][2 * kp], blo[0], acc[rt][0], 0, 0, 0);
                acc[rt][1] = __builtin_amdgcn_mfma_f32_16x16x32_fp8_fp8(areg[rt][2 * kp], blo[1], acc[rt][1], 0, 0, 0);
            }
            #pragma unroll
            for (int rt = 0; rt < 4; ++rt) {
                acc[rt][0] = __builtin_amdgcn_mfma_f32_16x16x32_fp8_fp8(areg[rt][2 * kp + 1], bhi[0], acc[rt][0], 0, 0, 0);
                acc[rt][1] = __builtin_amdgcn_mfma_f32_16x16x32_fp8_fp8(areg[rt][2 * kp + 1], bhi[1], acc[rt][1], 0, 0, 0);
            }
        }
    };

    auto EPI = [&](const f32x4 (&acc)[4][2], const float (&bias)[2]) {
        #pragma unroll
        for (int rt = 0; rt < 4; ++rt)
            #pragma unroll
            for (int r = 0; r < 4; ++r)
                rs[rt][r] += __builtin_amdgcn_exp2f(acc[rt][0][r] * L2E + bias[0])
                           + __builtin_amdgcn_exp2f(acc[rt][1][r] * L2E + bias[1]);
    };

    f32x4 accA[4][2], accB[4][2];
    float biasA[2], biasB[2];

    STAGE(t0, bpan0);
    __syncthreads();
    if (t0 + 1 < t1) STAGE(t0 + 1, bpan1);
    COMPUTE(bpan0, accA, biasA, t0);
    __syncthreads();

    int i = t0 + 1;
    bool lastA = true;
    while (i < t1) {
        {
            const unsigned char* bp = ((i - t0) & 1) ? bpan1 : bpan0;
            unsigned char*       st = ((i - t0) & 1) ? bpan0 : bpan1;
            if (i + 1 < t1) STAGE(i + 1, st);
            COMPUTE(bp, accB, biasB, i);
            EPI(accA, biasA);
            __syncthreads();
            lastA = false; ++i;
            if (i >= t1) break;
        }
        {
            const unsigned char* bp = ((i - t0) & 1) ? bpan1 : bpan0;
            unsigned char*       st = ((i - t0) & 1) ? bpan0 : bpan1;
            if (i + 1 < t1) STAGE(i + 1, st);
            COMPUTE(bp, accA, biasA, i);
            EPI(accB, biasB);
            __syncthreads();
            lastA = true; ++i;
        }
    }
    if (lastA) EPI(accA, biasA); else EPI(accB, biasB);

    const int cr = lane >> 4;
    #pragma unroll
    for (int rt = 0; rt < 4; ++rt)
        #pragma unroll
        for (int r = 0; r < 4; ++r) {
            const float v = row16_sum(rs[rt][r]);
            if (lm == 0)
                partial[(size_t)(grp * 4 + wc) * M_TOTAL + mw + rt * 16 + cr * 4 + r] = v;
        }
}

// ---------------------------------------------------------------------------
// Kernel 3: finalize (R14, unchanged).
// ---------------------------------------------------------------------------
__global__ __launch_bounds__(256) void finalize_kernel(const unsigned char* __restrict__ zsb8,
                                                       const unsigned char* __restrict__ wt8,
                                                       const float* __restrict__ vb,
                                                       const int* __restrict__ y,
                                                       const float* __restrict__ partial,
                                                       float* __restrict__ out) {
    const int tid  = threadIdx.x;
    const int lane = tid & 63;
    const int rw   = lane >> 4;
    const int kl   = lane & 15;
    const int row  = blockIdx.x * 16 + (tid >> 6) * 4 + rw;
    const int yrow = y[row];

    u32x4 za = *(const u32x4*)(zsb8 + (size_t)row * E + kl * 16);
    u32x4 wa = *(const u32x4*)(wt8 + (size_t)yrow * E + kl * 16);
    float acc = 0.f;
    #pragma unroll
    for (int q = 0; q < 4; ++q) {
        f32x2 a0 = fp8x2_to_f32<false>(za[q]), b0 = fp8x2_to_f32<false>(wa[q]);
        f32x2 a1 = fp8x2_to_f32<true>(za[q]),  b1 = fp8x2_to_f32<true>(wa[q]);
        acc += a0[0] * b0[0] + a0[1] * b0[1] + a1[0] * b1[0] + a1[1] * b1[1];
    }
    const float logit = row16_sum(acc) + vb[yrow];

    float ps = partial[(size_t)kl * M_TOTAL + row] + partial[(size_t)(kl + 16) * M_TOTAL + row];
    const float tot = row16_sum(ps);

    if (kl == 0) out[row] = logit - logf(tot);
}

// ---------------------------------------------------------------------------
extern "C" void kernel_launch(void* const* d_in, const int* in_sizes, int n_in,
                              void* d_out, int out_size, void* d_ws, size_t ws_size,
                              hipStream_t stream) {
    const float* latent  = (const float*)d_in[0];
    const float* vocab_w = (const float*)d_in[1];
    const float* vocab_b = (const float*)d_in[2];
    const int*   zi      = (const int*)d_in[3];
    const int*   y       = (const int*)d_in[4];
    float* out = (float*)d_out;

    char* ws = (char*)d_ws;
    float*         partial = (float*)(ws);                             // 512 KB
    unsigned char* zsb8    = (unsigned char*)(ws + 524288);            // 1 MB
    unsigned char* wt8     = (unsigned char*)(ws + 524288 + 1048576);  // 8 MB

    hipLaunchKernelGGL(traj_transpose_kernel, dim3(BATCH + 4 * (V / 64)), dim3(512), 0, stream,
                       latent, zi, vocab_w, zsb8, wt8);
    hipLaunchKernelGGL(gemm_lse_kernel, dim3(32 * NGRP), dim3(512), 0, stream,
                       zsb8, wt8, vocab_b, partial);
    hipLaunchKernelGGL(finalize_kernel, dim3(M_TOTAL / 16), dim3(256), 0, stream,
                       zsb8, wt8, vocab_b, y, partial, out);
}

// Round 18
// 144.468 us; speedup vs baseline: 6.3571x; 1.7332x over previous
//
#include <hip/hip_runtime.h>
#include <hip/hip_bf16.h>

#define BATCH 32
#define E 256
#define V 32000
#define NSTEP 128
#define M_TOTAL (BATCH * NSTEP)   // 4096
#define BM 128
#define BN2 128
#define NBT (V / BN2)             // 250 b-tiles
#define NGRP 8                    // bn groups (== XCDs)
#define L2E 1.4426950408889634f

typedef __attribute__((ext_vector_type(4))) float f32x4;
typedef __attribute__((ext_vector_type(2))) float f32x2;
typedef __attribute__((ext_vector_type(8))) short s16x8;
typedef __attribute__((ext_vector_type(4))) unsigned int u32x4;

static __device__ __forceinline__ short f2bf(float v) {
    __hip_bfloat16 h = __float2bfloat16(v);
    return *reinterpret_cast<short*>(&h);
}

static __device__ __forceinline__ unsigned char f2fp8(float v) {
    int p = __builtin_amdgcn_cvt_pk_fp8_f32(v, v, 0, false);
    return (unsigned char)(p & 0xff);
}
template<bool HI>
static __device__ __forceinline__ f32x2 fp8x2_to_f32(unsigned int x) {
    return __builtin_amdgcn_cvt_pk_f32_fp8((int)x, HI);
}

// frag-major byte position within a 256-B row: element e -> lk*64 + kk*8 + j
static __device__ __forceinline__ int fragpos(int e) {
    return ((e >> 3) & 3) * 64 + (e >> 5) * 8 + (e & 7);
}

static __device__ __forceinline__ long long ll2(unsigned int a, unsigned int b) {
    return (long long)(((unsigned long long)b << 32) | a);
}

static __device__ __forceinline__ void gload_lds16(const void* g, void* l) {
    __builtin_amdgcn_global_load_lds((const __attribute__((address_space(1))) void*)g,
                                     (__attribute__((address_space(3))) void*)l,
                                     16, 0, 0);
}

template<int CTRL>
static __device__ __forceinline__ float dpp_add(float v) {
    int i = __builtin_amdgcn_update_dpp(0, __builtin_bit_cast(int, v), CTRL, 0xF, 0xF, false);
    return v + __builtin_bit_cast(float, i);
}
static __device__ __forceinline__ float row16_sum(float v) {
    v = dpp_add<0x121>(v);
    v = dpp_add<0x122>(v);
    v = dpp_add<0x124>(v);
    v = dpp_add<0x128>(v);
    return v;
}

// ---------------------------------------------------------------------------
// Kernel 1 (merged): blocks 0..31 = RNN trajectory; blocks 32.. = vocab_w
// transpose -> frag-major fp8.
// Trajectory: LDS carries the UNSCALED iterate u (u_{s+1} = scale_{s-1} *
// W^T u_s) so the std/scale computation is one step behind and entirely off
// the critical path. One barrier/step; emits register-buffered, flushed
// every 8 steps.
// ---------------------------------------------------------------------------
__global__ __launch_bounds__(512, 2) void traj_transpose_kernel(
        const float* __restrict__ latent, const int* __restrict__ zi,
        const float* __restrict__ w,
        unsigned char* __restrict__ zsb8, unsigned char* __restrict__ wt8) {
    __shared__ float tile[64][65];              // transpose path
    __shared__ __align__(16) short zsh[2][E];   // traj: û (unscaled), dbuf
    __shared__ __align__(16) float red[2][16];  // traj: u-stats partials, dbuf

    const int tid = threadIdx.x;

    if (blockIdx.x >= BATCH) {
        const int bb = blockIdx.x - BATCH;   // 0..1999
        const int k0 = (bb & 3) * 64;
        const int n0 = (bb >> 2) * 64;
        const int c  = tid & 63;
        const int r8 = tid >> 6;
        #pragma unroll
        for (int r = r8; r < 64; r += 8)
            tile[r][c] = w[(size_t)(k0 + r) * V + n0 + c];
        __syncthreads();
        const int fp = fragpos(k0 + c);
        #pragma unroll
        for (int r = r8; r < 64; r += 8)
            wt8[(size_t)(n0 + r) * E + fp] = f2fp8(tile[c][r]);
        return;
    }

    // ---- trajectory path: one batch per block, 8 waves ----
    const int b    = blockIdx.x;
    const int lane = tid & 63;
    const int wv   = tid >> 6;
    const int lm   = lane & 15;
    const int g    = lane >> 4;
    const float* tr = latent + (size_t)zi[b] * (E * E);

    s16x8 bfrag[2][8];
    #pragma unroll
    for (int nt = 0; nt < 2; ++nt)
        #pragma unroll
        for (int kk = 0; kk < 8; ++kk) {
            s16x8 fr;
            #pragma unroll
            for (int j = 0; j < 8; ++j)
                fr[j] = f2bf(tr[(size_t)(kk * 32 + g * 8 + j) * E + wv * 32 + nt * 16 + lm]);
            bfrag[nt][kk] = fr;
        }

    // û_0 = bf16(z_0) (u_0 = z_0, scale_{-1} = 1)
    if (tid < E) zsh[0][tid] = f2bf(tr[tid]);

    {   // stats of u_0 -> red[1] (step 0 reads red[(0+1)&1])
        float v = (tid < E) ? tr[tid] : 0.f;
        float a = row16_sum(v), a2 = row16_sum(v * v);
        a  += __shfl_xor(a, 16);  a2 += __shfl_xor(a2, 16);
        a  += __shfl_xor(a, 32);  a2 += __shfl_xor(a2, 32);
        if (lane == 0) { red[1][wv] = a; red[1][8 + wv] = a2; }
    }
    __syncthreads();

    float scale_prev = 1.0f;   // scale_{s-1}

    const int p0i = fragpos(wv * 32 + lm);
    const int p1i = fragpos(wv * 32 + 16 + lm);

    for (int tb = 0; tb < NSTEP; tb += 8) {
        unsigned char eb0[8], eb1[8];   // static-indexed only -> registers

        #pragma unroll
        for (int s = 0; s < 8; ++s) {
            const int t = tb + s;
            const short* zrd = zsh[t & 1];
            s16x8 a[8];
            #pragma unroll
            for (int kk = 0; kk < 8; ++kk)
                a[kk] = *(const s16x8*)((const char*)zrd + kk * 64 + g * 16);

            // scale_s from u_s stats (published at step s-1) -- off-path,
            // overlaps the MFMA chain below.
            const float* rd = red[(t + 1) & 1];
            f32x4 q0 = *(const f32x4*)&rd[0], q1 = *(const f32x4*)&rd[4];
            f32x4 v0 = *(const f32x4*)&rd[8], v1 = *(const f32x4*)&rd[12];
            float ts  = (q0[0]+q0[1]+q0[2]+q0[3]) + (q1[0]+q1[1]+q1[2]+q1[3]);
            float ts2 = (v0[0]+v0[1]+v0[2]+v0[3]) + (v1[0]+v1[1]+v1[2]+v1[3]);
            float var = fmaxf((ts2 - ts * ts * (1.0f / 256.0f)) * (1.0f / 255.0f), 0.f);
            const float scale_cur = 0.113f / (1e-5f + scale_prev * sqrtf(var));

            // m = W^T u_s  (two independent chains per tile)
            f32x4 a0l = {}, a0h = {}, a1l = {}, a1h = {};
            #pragma unroll
            for (int kk = 0; kk < 4; ++kk) {
                a0l = __builtin_amdgcn_mfma_f32_16x16x32_bf16(a[kk], bfrag[0][kk], a0l, 0, 0, 0);
                a1l = __builtin_amdgcn_mfma_f32_16x16x32_bf16(a[kk], bfrag[1][kk], a1l, 0, 0, 0);
            }
            #pragma unroll
            for (int kk = 4; kk < 8; ++kk) {
                a0h = __builtin_amdgcn_mfma_f32_16x16x32_bf16(a[kk], bfrag[0][kk], a0h, 0, 0, 0);
                a1h = __builtin_amdgcn_mfma_f32_16x16x32_bf16(a[kk], bfrag[1][kk], a1h, 0, 0, 0);
            }

            // u_{s+1} = scale_{s-1} * m ;  z_{s+1} = scale_s * u_{s+1}
            const float u0 = scale_prev * (a0l[0] + a0h[0]);
            const float u1 = scale_prev * (a1l[0] + a1h[0]);
            if (g == 0) {
                zsh[(t + 1) & 1][wv * 32 + lm]      = f2bf(u0);
                zsh[(t + 1) & 1][wv * 32 + 16 + lm] = f2bf(u1);
                eb0[s] = f2fp8(scale_cur * u0);
                eb1[s] = f2fp8(scale_cur * u1);
            }

            // stats of u_{s+1} for step s+1 (consumed one step later)
            float su  = row16_sum(u0 + u1);
            float su2 = row16_sum(u0 * u0 + u1 * u1);
            if (lane == 0) { red[t & 1][wv] = su; red[t & 1][8 + wv] = su2; }

            scale_prev = scale_cur;
            __syncthreads();
        }

        // ---- flush: 16 byte-stores, drained once at the next barrier ----
        if (g == 0) {
            unsigned char* zr = zsb8 + ((size_t)b * NSTEP + tb) * E;
            #pragma unroll
            for (int s = 0; s < 8; ++s) {
                zr[s * E + p0i] = eb0[s];
                zr[s * E + p1i] = eb1[s];
            }
        }
    }
}

// ---------------------------------------------------------------------------
// Kernel 2: persistent fp8 GEMM, 2-deep acc pipeline (unchanged).
// ---------------------------------------------------------------------------
__global__ __launch_bounds__(512, 2) void gemm_lse_kernel(const unsigned char* __restrict__ zsb8,
                                                          const unsigned char* __restrict__ wt8,
                                                          const float* __restrict__ vb,
                                                          float* __restrict__ partial) {
    __shared__ unsigned char bpan0[BN2 * E];    // 32 KB
    __shared__ unsigned char bpan1[BN2 * E];    // 32 KB

    const int tid  = threadIdx.x;
    const int lane = tid & 63;
    const int w    = tid >> 6;         // 0..7
    const int grp  = blockIdx.x & 7;
    const int bm   = blockIdx.x >> 3;  // 0..31
    const int m0   = bm * BM;
    const int t0   = (NBT * grp) >> 3;
    const int t1   = (NBT * (grp + 1)) >> 3;

    const int wr = w >> 2, wc = w & 3;
    const int lm = lane & 15, lk = lane >> 4;
    const int mw = m0 + wr * 64;

    long long areg[4][8];
    #pragma unroll
    for (int rt = 0; rt < 4; ++rt)
        #pragma unroll
        for (int kp = 0; kp < 4; ++kp) {
            u32x4 v = *(const u32x4*)(zsb8 + (size_t)(mw + rt * 16 + lm) * E + lk * 64 + kp * 16);
            areg[rt][2 * kp]     = ll2(v[0], v[1]);
            areg[rt][2 * kp + 1] = ll2(v[2], v[3]);
        }

    float rs[4][4] = {};

    auto STAGE = [&](int tile, unsigned char* dst) {
        const size_t gbase = (size_t)(tile * BN2) * E;
        #pragma unroll
        for (int j = 0; j < 4; ++j) {
            const int c   = j * 512 + tid;
            const int row = c >> 4;
            const int gsl = ((c & 15) - row) & 15;
            gload_lds16(wt8 + gbase + (size_t)row * E + gsl * 16, dst + c * 16);
        }
    };

    auto COMPUTE = [&](const unsigned char* bp, f32x4 (&acc)[4][2], float (&bias)[2], int tile) {
        const int n0 = tile * BN2;
        bias[0] = vb[n0 + wc * 32 + lm] * L2E;
        bias[1] = vb[n0 + wc * 32 + 16 + lm] * L2E;
        #pragma unroll
        for (int rt = 0; rt < 4; ++rt) { acc[rt][0] = (f32x4){}; acc[rt][1] = (f32x4){}; }
        #pragma unroll
        for (int kp = 0; kp < 4; ++kp) {
            long long blo[2], bhi[2];
            #pragma unroll
            for (int nt = 0; nt < 2; ++nt) {
                const int rn   = wc * 32 + nt * 16 + lm;
                const int slot = (lk * 4 + kp + rn) & 15;
                u32x4 bv = *(const u32x4*)(bp + rn * 256 + slot * 16);
                blo[nt] = ll2(bv[0], bv[1]);
                bhi[nt] = ll2(bv[2], bv[3]);
            }
            #pragma unroll
            for (int rt = 0; rt < 4; ++rt) {
                acc[rt][0] = __builtin_amdgcn_mfma_f32_16x16x32_fp8_fp8(areg[rt][2 * kp], blo[0], acc[rt][0], 0, 0, 0);
                acc[rt][1] = __builtin_amdgcn_mfma_f32_16x16x32_fp8_fp8(areg[rt][2 * kp], blo[1], acc[rt][1], 0, 0, 0);
            }
            #pragma unroll
            for (int rt = 0; rt < 4; ++rt) {
                acc[rt][0] = __builtin_amdgcn_mfma_f32_16x16x32_fp8_fp8(areg[rt][2 * kp + 1], bhi[0], acc[rt][0], 0, 0, 0);
                acc[rt][1] = __builtin_amdgcn_mfma_f32_16x16x32_fp8_fp8(areg[rt][2 * kp + 1], bhi[1], acc[rt][1], 0, 0, 0);
            }
        }
    };

    auto EPI = [&](const f32x4 (&acc)[4][2], const float (&bias)[2]) {
        #pragma unroll
        for (int rt = 0; rt < 4; ++rt)
            #pragma unroll
            for (int r = 0; r < 4; ++r)
                rs[rt][r] += __builtin_amdgcn_exp2f(acc[rt][0][r] * L2E + bias[0])
                           + __builtin_amdgcn_exp2f(acc[rt][1][r] * L2E + bias[1]);
    };

    f32x4 accA[4][2], accB[4][2];
    float biasA[2], biasB[2];

    STAGE(t0, bpan0);
    __syncthreads();
    if (t0 + 1 < t1) STAGE(t0 + 1, bpan1);
    COMPUTE(bpan0, accA, biasA, t0);
    __syncthreads();

    int i = t0 + 1;
    bool lastA = true;
    while (i < t1) {
        {
            const unsigned char* bp = ((i - t0) & 1) ? bpan1 : bpan0;
            unsigned char*       st = ((i - t0) & 1) ? bpan0 : bpan1;
            if (i + 1 < t1) STAGE(i + 1, st);
            COMPUTE(bp, accB, biasB, i);
            EPI(accA, biasA);
            __syncthreads();
            lastA = false; ++i;
            if (i >= t1) break;
        }
        {
            const unsigned char* bp = ((i - t0) & 1) ? bpan1 : bpan0;
            unsigned char*       st = ((i - t0) & 1) ? bpan0 : bpan1;
            if (i + 1 < t1) STAGE(i + 1, st);
            COMPUTE(bp, accA, biasA, i);
            EPI(accB, biasB);
            __syncthreads();
            lastA = true; ++i;
        }
    }
    if (lastA) EPI(accA, biasA); else EPI(accB, biasB);

    const int cr = lane >> 4;
    #pragma unroll
    for (int rt = 0; rt < 4; ++rt)
        #pragma unroll
        for (int r = 0; r < 4; ++r) {
            const float v = row16_sum(rs[rt][r]);
            if (lm == 0)
                partial[(size_t)(grp * 4 + wc) * M_TOTAL + mw + rt * 16 + cr * 4 + r] = v;
        }
}

// ---------------------------------------------------------------------------
// Kernel 3: finalize (unchanged).
// ---------------------------------------------------------------------------
__global__ __launch_bounds__(256) void finalize_kernel(const unsigned char* __restrict__ zsb8,
                                                       const unsigned char* __restrict__ wt8,
                                                       const float* __restrict__ vb,
                                                       const int* __restrict__ y,
                                                       const float* __restrict__ partial,
                                                       float* __restrict__ out) {
    const int tid  = threadIdx.x;
    const int lane = tid & 63;
    const int rw   = lane >> 4;
    const int kl   = lane & 15;
    const int row  = blockIdx.x * 16 + (tid >> 6) * 4 + rw;
    const int yrow = y[row];

    u32x4 za = *(const u32x4*)(zsb8 + (size_t)row * E + kl * 16);
    u32x4 wa = *(const u32x4*)(wt8 + (size_t)yrow * E + kl * 16);
    float acc = 0.f;
    #pragma unroll
    for (int q = 0; q < 4; ++q) {
        f32x2 a0 = fp8x2_to_f32<false>(za[q]), b0 = fp8x2_to_f32<false>(wa[q]);
        f32x2 a1 = fp8x2_to_f32<true>(za[q]),  b1 = fp8x2_to_f32<true>(wa[q]);
        acc += a0[0] * b0[0] + a0[1] * b0[1] + a1[0] * b1[0] + a1[1] * b1[1];
    }
    const float logit = row16_sum(acc) + vb[yrow];

    float ps = partial[(size_t)kl * M_TOTAL + row] + partial[(size_t)(kl + 16) * M_TOTAL + row];
    const float tot = row16_sum(ps);

    if (kl == 0) out[row] = logit - logf(tot);
}

// ---------------------------------------------------------------------------
extern "C" void kernel_launch(void* const* d_in, const int* in_sizes, int n_in,
                              void* d_out, int out_size, void* d_ws, size_t ws_size,
                              hipStream_t stream) {
    const float* latent  = (const float*)d_in[0];
    const float* vocab_w = (const float*)d_in[1];
    const float* vocab_b = (const float*)d_in[2];
    const int*   zi      = (const int*)d_in[3];
    const int*   y       = (const int*)d_in[4];
    float* out = (float*)d_out;

    char* ws = (char*)d_ws;
    float*         partial = (float*)(ws);                             // 512 KB
    unsigned char* zsb8    = (unsigned char*)(ws + 524288);            // 1 MB
    unsigned char* wt8     = (unsigned char*)(ws + 524288 + 1048576);  // 8 MB

    hipLaunchKernelGGL(traj_transpose_kernel, dim3(BATCH + 4 * (V / 64)), dim3(512), 0, stream,
                       latent, zi, vocab_w, zsb8, wt8);
    hipLaunchKernelGGL(gemm_lse_kernel, dim3(32 * NGRP), dim3(512), 0, stream,
                       zsb8, wt8, vocab_b, partial);
    hipLaunchKernelGGL(finalize_kernel, dim3(M_TOTAL / 16), dim3(256), 0, stream,
                       zsb8, wt8, vocab_b, y, partial, out);
}

// Round 19
// 143.628 us; speedup vs baseline: 6.3943x; 1.0058x over previous
//
#include <hip/hip_runtime.h>
#include <hip/hip_bf16.h>

#define BATCH 32
#define E 256
#define V 32000
#define NSTEP 128
#define M_TOTAL (BATCH * NSTEP)   // 4096
#define BM 128
#define BN2 128
#define NBT (V / BN2)             // 250 b-tiles
#define NGRP 8                    // bn groups (== XCDs)
#define L2E 1.4426950408889634f

typedef __attribute__((ext_vector_type(4))) float f32x4;
typedef __attribute__((ext_vector_type(2))) float f32x2;
typedef __attribute__((ext_vector_type(8))) short s16x8;
typedef __attribute__((ext_vector_type(4))) unsigned int u32x4;

static __device__ __forceinline__ short f2bf(float v) {
    __hip_bfloat16 h = __float2bfloat16(v);
    return *reinterpret_cast<short*>(&h);
}

static __device__ __forceinline__ unsigned char f2fp8(float v) {
    int p = __builtin_amdgcn_cvt_pk_fp8_f32(v, v, 0, false);
    return (unsigned char)(p & 0xff);
}
template<bool HI>
static __device__ __forceinline__ f32x2 fp8x2_to_f32(unsigned int x) {
    return __builtin_amdgcn_cvt_pk_f32_fp8((int)x, HI);
}

// frag-major byte position within a 256-B row: element e -> lk*64 + kk*8 + j
static __device__ __forceinline__ int fragpos(int e) {
    return ((e >> 3) & 3) * 64 + (e >> 5) * 8 + (e & 7);
}

static __device__ __forceinline__ long long ll2(unsigned int a, unsigned int b) {
    return (long long)(((unsigned long long)b << 32) | a);
}

static __device__ __forceinline__ void gload_lds16(const void* g, void* l) {
    __builtin_amdgcn_global_load_lds((const __attribute__((address_space(1))) void*)g,
                                     (__attribute__((address_space(3))) void*)l,
                                     16, 0, 0);
}

template<int CTRL>
static __device__ __forceinline__ float dpp_add(float v) {
    int i = __builtin_amdgcn_update_dpp(0, __builtin_bit_cast(int, v), CTRL, 0xF, 0xF, false);
    return v + __builtin_bit_cast(float, i);
}
static __device__ __forceinline__ float row16_sum(float v) {
    v = dpp_add<0x121>(v);
    v = dpp_add<0x122>(v);
    v = dpp_add<0x124>(v);
    v = dpp_add<0x128>(v);
    return v;
}

// ---------------------------------------------------------------------------
// Kernel 1 (merged), 256 threads: blocks 0..31 = RNN trajectory with FOUR
// waves x FOUR output tiles each (per-CU broadcast ds_read traffic halved vs
// the 8-wave version: A-fragments are identical across waves, so fewer waves
// = fewer redundant reads). blocks 32.. = vocab_w transpose -> frag-major fp8.
// Traj math identical to R14: unscaled iterate u in LDS, scale recursion one
// step behind, emits register-buffered and flushed every 8 steps.
// ---------------------------------------------------------------------------
__global__ __launch_bounds__(256, 1) void traj_transpose_kernel(
        const float* __restrict__ latent, const int* __restrict__ zi,
        const float* __restrict__ w,
        unsigned char* __restrict__ zsb8, unsigned char* __restrict__ wt8) {
    __shared__ float tile[64][65];              // transpose path
    __shared__ __align__(16) short zsh[2][E];   // traj: û (unscaled), dbuf
    __shared__ __align__(16) float red[2][8];   // traj: u-stats partials, dbuf

    const int tid = threadIdx.x;

    if (blockIdx.x >= BATCH) {
        const int bb = blockIdx.x - BATCH;   // 0..1999
        const int k0 = (bb & 3) * 64;
        const int n0 = (bb >> 2) * 64;
        const int c  = tid & 63;
        const int r4 = tid >> 6;             // 0..3
        #pragma unroll
        for (int r = r4; r < 64; r += 4)
            tile[r][c] = w[(size_t)(k0 + r) * V + n0 + c];
        __syncthreads();
        const int fp = fragpos(k0 + c);
        #pragma unroll
        for (int r = r4; r < 64; r += 4)
            wt8[(size_t)(n0 + r) * E + fp] = f2fp8(tile[c][r]);
        return;
    }

    // ---- trajectory path: one batch per block, 4 waves x 64 cols each ----
    const int b    = blockIdx.x;
    const int lane = tid & 63;
    const int wv   = tid >> 6;       // 0..3, owns cols [64wv, 64wv+64)
    const int lm   = lane & 15;
    const int g    = lane >> 4;
    const float* tr = latent + (size_t)zi[b] * (E * E);

    // B-frags of W for 4 tiles: B[n][k] = W[k][n]
    s16x8 bfrag[4][8];
    #pragma unroll
    for (int nt = 0; nt < 4; ++nt)
        #pragma unroll
        for (int kk = 0; kk < 8; ++kk) {
            s16x8 fr;
            #pragma unroll
            for (int j = 0; j < 8; ++j)
                fr[j] = f2bf(tr[(size_t)(kk * 32 + g * 8 + j) * E + wv * 64 + nt * 16 + lm]);
            bfrag[nt][kk] = fr;
        }

    // û_0 = bf16(z_0) (u_0 = z_0, scale_{-1} = 1)
    zsh[0][tid] = f2bf(tr[tid]);

    {   // stats of u_0 -> red[1] (step 0 reads red[(0+1)&1])
        float v = tr[tid];
        float a = row16_sum(v), a2 = row16_sum(v * v);
        a  += __shfl_xor(a, 16);  a2 += __shfl_xor(a2, 16);
        a  += __shfl_xor(a, 32);  a2 += __shfl_xor(a2, 32);
        if (lane == 0) { red[1][wv] = a; red[1][4 + wv] = a2; }
    }
    __syncthreads();

    float scale_prev = 1.0f;   // scale_{s-1}

    int pp[4];
    #pragma unroll
    for (int nt = 0; nt < 4; ++nt) pp[nt] = fragpos(wv * 64 + nt * 16 + lm);

    for (int tb = 0; tb < NSTEP; tb += 8) {
        unsigned char eb[4][8];   // static-indexed only -> registers

        #pragma unroll
        for (int s = 0; s < 8; ++s) {
            const int t = tb + s;
            const short* zrd = zsh[t & 1];
            s16x8 a[8];
            #pragma unroll
            for (int kk = 0; kk < 8; ++kk)
                a[kk] = *(const s16x8*)((const char*)zrd + kk * 64 + g * 16);

            // scale_s from u_s stats (published at step s-1) -- off-path.
            const float* rd = red[(t + 1) & 1];
            f32x4 q = *(const f32x4*)&rd[0];
            f32x4 v4 = *(const f32x4*)&rd[4];
            float ts  = (q[0] + q[1]) + (q[2] + q[3]);
            float ts2 = (v4[0] + v4[1]) + (v4[2] + v4[3]);
            float var = fmaxf((ts2 - ts * ts * (1.0f / 256.0f)) * (1.0f / 255.0f), 0.f);
            const float scale_cur = 0.113f / (1e-5f + scale_prev * sqrtf(var));

            // m = W^T u_s : 4 tiles x 2 independent 4-deep chains
            f32x4 lo[4] = {}, hi[4] = {};
            #pragma unroll
            for (int kk = 0; kk < 4; ++kk)
                #pragma unroll
                for (int nt = 0; nt < 4; ++nt)
                    lo[nt] = __builtin_amdgcn_mfma_f32_16x16x32_bf16(a[kk], bfrag[nt][kk], lo[nt], 0, 0, 0);
            #pragma unroll
            for (int kk = 4; kk < 8; ++kk)
                #pragma unroll
                for (int nt = 0; nt < 4; ++nt)
                    hi[nt] = __builtin_amdgcn_mfma_f32_16x16x32_bf16(a[kk], bfrag[nt][kk], hi[nt], 0, 0, 0);

            // u_{s+1} = scale_{s-1} * m ;  z_{s+1} = scale_s * u_{s+1}
            float u[4];
            #pragma unroll
            for (int nt = 0; nt < 4; ++nt) u[nt] = scale_prev * (lo[nt][0] + hi[nt][0]);

            if (g == 0) {
                #pragma unroll
                for (int nt = 0; nt < 4; ++nt) {
                    zsh[(t + 1) & 1][wv * 64 + nt * 16 + lm] = f2bf(u[nt]);
                    eb[nt][s] = f2fp8(scale_cur * u[nt]);
                }
            }

            // stats of u_{s+1} for step s+1 (consumed one step later)
            float su  = row16_sum((u[0] + u[1]) + (u[2] + u[3]));
            float su2 = row16_sum((u[0] * u[0] + u[1] * u[1]) + (u[2] * u[2] + u[3] * u[3]));
            if (lane == 0) { red[t & 1][wv] = su; red[t & 1][4 + wv] = su2; }

            scale_prev = scale_cur;
            __syncthreads();
        }

        // ---- flush: byte-stores, drained once at the next barrier ----
        if (g == 0) {
            unsigned char* zr = zsb8 + ((size_t)b * NSTEP + tb) * E;
            #pragma unroll
            for (int s = 0; s < 8; ++s)
                #pragma unroll
                for (int nt = 0; nt < 4; ++nt)
                    zr[s * E + pp[nt]] = eb[nt][s];
        }
    }
}

// ---------------------------------------------------------------------------
// Kernel 2: persistent fp8 GEMM, 2-deep acc pipeline (unchanged).
// ---------------------------------------------------------------------------
__global__ __launch_bounds__(512, 2) void gemm_lse_kernel(const unsigned char* __restrict__ zsb8,
                                                          const unsigned char* __restrict__ wt8,
                                                          const float* __restrict__ vb,
                                                          float* __restrict__ partial) {
    __shared__ unsigned char bpan0[BN2 * E];    // 32 KB
    __shared__ unsigned char bpan1[BN2 * E];    // 32 KB

    const int tid  = threadIdx.x;
    const int lane = tid & 63;
    const int w    = tid >> 6;         // 0..7
    const int grp  = blockIdx.x & 7;
    const int bm   = blockIdx.x >> 3;  // 0..31
    const int m0   = bm * BM;
    const int t0   = (NBT * grp) >> 3;
    const int t1   = (NBT * (grp + 1)) >> 3;

    const int wr = w >> 2, wc = w & 3;
    const int lm = lane & 15, lk = lane >> 4;
    const int mw = m0 + wr * 64;

    long long areg[4][8];
    #pragma unroll
    for (int rt = 0; rt < 4; ++rt)
        #pragma unroll
        for (int kp = 0; kp < 4; ++kp) {
            u32x4 v = *(const u32x4*)(zsb8 + (size_t)(mw + rt * 16 + lm) * E + lk * 64 + kp * 16);
            areg[rt][2 * kp]     = ll2(v[0], v[1]);
            areg[rt][2 * kp + 1] = ll2(v[2], v[3]);
        }

    float rs[4][4] = {};

    auto STAGE = [&](int tile, unsigned char* dst) {
        const size_t gbase = (size_t)(tile * BN2) * E;
        #pragma unroll
        for (int j = 0; j < 4; ++j) {
            const int c   = j * 512 + tid;
            const int row = c >> 4;
            const int gsl = ((c & 15) - row) & 15;
            gload_lds16(wt8 + gbase + (size_t)row * E + gsl * 16, dst + c * 16);
        }
    };

    auto COMPUTE = [&](const unsigned char* bp, f32x4 (&acc)[4][2], float (&bias)[2], int tile) {
        const int n0 = tile * BN2;
        bias[0] = vb[n0 + wc * 32 + lm] * L2E;
        bias[1] = vb[n0 + wc * 32 + 16 + lm] * L2E;
        #pragma unroll
        for (int rt = 0; rt < 4; ++rt) { acc[rt][0] = (f32x4){}; acc[rt][1] = (f32x4){}; }
        #pragma unroll
        for (int kp = 0; kp < 4; ++kp) {
            long long blo[2], bhi[2];
            #pragma unroll
            for (int nt = 0; nt < 2; ++nt) {
                const int rn   = wc * 32 + nt * 16 + lm;
                const int slot = (lk * 4 + kp + rn) & 15;
                u32x4 bv = *(const u32x4*)(bp + rn * 256 + slot * 16);
                blo[nt] = ll2(bv[0], bv[1]);
                bhi[nt] = ll2(bv[2], bv[3]);
            }
            #pragma unroll
            for (int rt = 0; rt < 4; ++rt) {
                acc[rt][0] = __builtin_amdgcn_mfma_f32_16x16x32_fp8_fp8(areg[rt][2 * kp], blo[0], acc[rt][0], 0, 0, 0);
                acc[rt][1] = __builtin_amdgcn_mfma_f32_16x16x32_fp8_fp8(areg[rt][2 * kp], blo[1], acc[rt][1], 0, 0, 0);
            }
            #pragma unroll
            for (int rt = 0; rt < 4; ++rt) {
                acc[rt][0] = __builtin_amdgcn_mfma_f32_16x16x32_fp8_fp8(areg[rt][2 * kp + 1], bhi[0], acc[rt][0], 0, 0, 0);
                acc[rt][1] = __builtin_amdgcn_mfma_f32_16x16x32_fp8_fp8(areg[rt][2 * kp + 1], bhi[1], acc[rt][1], 0, 0, 0);
            }
        }
    };

    auto EPI = [&](const f32x4 (&acc)[4][2], const float (&bias)[2]) {
        #pragma unroll
        for (int rt = 0; rt < 4; ++rt)
            #pragma unroll
            for (int r = 0; r < 4; ++r)
                rs[rt][r] += __builtin_amdgcn_exp2f(acc[rt][0][r] * L2E + bias[0])
                           + __builtin_amdgcn_exp2f(acc[rt][1][r] * L2E + bias[1]);
    };

    f32x4 accA[4][2], accB[4][2];
    float biasA[2], biasB[2];

    STAGE(t0, bpan0);
    __syncthreads();
    if (t0 + 1 < t1) STAGE(t0 + 1, bpan1);
    COMPUTE(bpan0, accA, biasA, t0);
    __syncthreads();

    int i = t0 + 1;
    bool lastA = true;
    while (i < t1) {
        {
            const unsigned char* bp = ((i - t0) & 1) ? bpan1 : bpan0;
            unsigned char*       st = ((i - t0) & 1) ? bpan0 : bpan1;
            if (i + 1 < t1) STAGE(i + 1, st);
            COMPUTE(bp, accB, biasB, i);
            EPI(accA, biasA);
            __syncthreads();
            lastA = false; ++i;
            if (i >= t1) break;
        }
        {
            const unsigned char* bp = ((i - t0) & 1) ? bpan1 : bpan0;
            unsigned char*       st = ((i - t0) & 1) ? bpan0 : bpan1;
            if (i + 1 < t1) STAGE(i + 1, st);
            COMPUTE(bp, accA, biasA, i);
            EPI(accB, biasB);
            __syncthreads();
            lastA = true; ++i;
        }
    }
    if (lastA) EPI(accA, biasA); else EPI(accB, biasB);

    const int cr = lane >> 4;
    #pragma unroll
    for (int rt = 0; rt < 4; ++rt)
        #pragma unroll
        for (int r = 0; r < 4; ++r) {
            const float v = row16_sum(rs[rt][r]);
            if (lm == 0)
                partial[(size_t)(grp * 4 + wc) * M_TOTAL + mw + rt * 16 + cr * 4 + r] = v;
        }
}

// ---------------------------------------------------------------------------
// Kernel 3: finalize (unchanged).
// ---------------------------------------------------------------------------
__global__ __launch_bounds__(256) void finalize_kernel(const unsigned char* __restrict__ zsb8,
                                                       const unsigned char* __restrict__ wt8,
                                                       const float* __restrict__ vb,
                                                       const int* __restrict__ y,
                                                       const float* __restrict__ partial,
                                                       float* __restrict__ out) {
    const int tid  = threadIdx.x;
    const int lane = tid & 63;
    const int rw   = lane >> 4;
    const int kl   = lane & 15;
    const int row  = blockIdx.x * 16 + (tid >> 6) * 4 + rw;
    const int yrow = y[row];

    u32x4 za = *(const u32x4*)(zsb8 + (size_t)row * E + kl * 16);
    u32x4 wa = *(const u32x4*)(wt8 + (size_t)yrow * E + kl * 16);
    float acc = 0.f;
    #pragma unroll
    for (int q = 0; q < 4; ++q) {
        f32x2 a0 = fp8x2_to_f32<false>(za[q]), b0 = fp8x2_to_f32<false>(wa[q]);
        f32x2 a1 = fp8x2_to_f32<true>(za[q]),  b1 = fp8x2_to_f32<true>(wa[q]);
        acc += a0[0] * b0[0] + a0[1] * b0[1] + a1[0] * b1[0] + a1[1] * b1[1];
    }
    const float logit = row16_sum(acc) + vb[yrow];

    float ps = partial[(size_t)kl * M_TOTAL + row] + partial[(size_t)(kl + 16) * M_TOTAL + row];
    const float tot = row16_sum(ps);

    if (kl == 0) out[row] = logit - logf(tot);
}

// ---------------------------------------------------------------------------
extern "C" void kernel_launch(void* const* d_in, const int* in_sizes, int n_in,
                              void* d_out, int out_size, void* d_ws, size_t ws_size,
                              hipStream_t stream) {
    const float* latent  = (const float*)d_in[0];
    const float* vocab_w = (const float*)d_in[1];
    const float* vocab_b = (const float*)d_in[2];
    const int*   zi      = (const int*)d_in[3];
    const int*   y       = (const int*)d_in[4];
    float* out = (float*)d_out;

    char* ws = (char*)d_ws;
    float*         partial = (float*)(ws);                             // 512 KB
    unsigned char* zsb8    = (unsigned char*)(ws + 524288);            // 1 MB
    unsigned char* wt8     = (unsigned char*)(ws + 524288 + 1048576);  // 8 MB

    hipLaunchKernelGGL(traj_transpose_kernel, dim3(BATCH + 4 * (V / 64)), dim3(256), 0, stream,
                       latent, zi, vocab_w, zsb8, wt8);
    hipLaunchKernelGGL(gemm_lse_kernel, dim3(32 * NGRP), dim3(512), 0, stream,
                       zsb8, wt8, vocab_b, partial);
    hipLaunchKernelGGL(finalize_kernel, dim3(M_TOTAL / 16), dim3(256), 0, stream,
                       zsb8, wt8, vocab_b, y, partial, out);
}